// Round 10
// baseline (797.020 us; speedup 1.0000x reference)
//
#include <hip/hip_runtime.h>

#define T_STEPS 100
#define BATCH   512
#define FIN     784
#define O1      100
#define O2      10
#define KC1     28      // K-chunk (784 = 28 * 28)
#define NC1     (FIN / KC1)

typedef __attribute__((ext_vector_type(4))) double f64x4;

// Raw block barrier draining only LDS (lgkmcnt); global loads stay in flight.
__device__ __forceinline__ void block_sync_lds() {
  __builtin_amdgcn_sched_barrier(0);
  asm volatile("s_waitcnt lgkmcnt(0)" ::: "memory");
  __builtin_amdgcn_s_barrier();
  __builtin_amdgcn_sched_barrier(0);
}

// ---------------------------------------------------------------------------
// K1 v8: fused C-mean + f64 MFMA GEMM, 2-t N-tile.
//   I1T[t][o][b] = sum_f 0.5*(in[b,t,f,0]+in[b,t,f,1]) * W1[f,o]
// Rounds 7/8/9 all sat at MfmaUtil ~50% with ~98 MFMA per block-chunk against
// the same 2-barrier + W-load + staging overhead -> the lever is MFMA work
// per chunk. v8: block covers N = (2 t) x (32 b) = 64 output cols; the SAME
// W fragment feeds both t-slices: per q-group a wave does 2 ds_reads + 8
// MFMAs (56 MFMA/wave-chunk; 196/block-chunk = 2x round 8) for the SAME 28
// W loads and 2 barriers. W loads issued BEFORE ds_write (ds_write+barrier
// covers their L1/L2 latency; ist is older in the vmcnt queue, so the
// ds_write's ist-wait leaves W in flight, and the compute-phase W-wait
// (vmcnt(4)) leaves the input prefetch in flight).
// Waves (wN=w&1, wo=w>>1): wN -> t-slice, wo -> o-tiles {0,16,32,48} or
// {64,80,84} (84 overlaps 80: duplicate stores bitwise identical).
// Grid 16x50 = 800 blocks -> all co-resident at 4 blocks/CU, no tail.
// ---------------------------------------------------------------------------
__global__ __launch_bounds__(256, 4) void k1_mfma(const float* __restrict__ in,
                                                  const float* __restrict__ W1,
                                                  double* __restrict__ I1T) {
  __shared__ double AI[KC1][69];    // [f-in-chunk][n], n = tsub*32 + b; pad 69
  const int tid = threadIdx.x;
  const int l   = tid & 63;
  const int w   = tid >> 6;
  const int wN  = w & 1;            // t-slice
  const int wo  = w >> 1;           // o-group
  const int r16 = l & 15;
  const int q16 = l >> 4;
  const int b0  = (int)blockIdx.x * 32;
  const int t0  = (int)blockIdx.y * 2;

  // --- input staging: 64 n-rows x 14 float4 = 896 float4 over 256 threads ---
  bool iact[4]; int irow[4], iq[4]; const float* ibp[4];
#pragma unroll
  for (int p = 0; p < 4; ++p) {
    const int i = p * 256 + tid;
    iact[p] = (i < 896);
    const int nrow = iact[p] ? i / 14 : 0;
    iq[p]   = (iact[p] ? i : 0) - nrow * 14;
    irow[p] = nrow;
    const int tsub = nrow >> 5, brow = nrow & 31;
    ibp[p]  = in + ((size_t)(b0 + brow) * T_STEPS + (t0 + tsub)) * (FIN * 2) + iq[p] * 4;
  }

  // prologue: issue chunk-0 input loads (latency hidden under the probe)
  float4 ist[4];
#pragma unroll
  for (int p = 0; p < 4; ++p) if (iact[p]) ist[p] = *reinterpret_cast<const float4*>(ibp[p]);

  // --- in-kernel D-layout probe (validated rounds 3-9) ---
  const f64x4 z = {0.0, 0.0, 0.0, 0.0};
  f64x4 pr = __builtin_amdgcn_mfma_f64_16x16x4f64((double)r16, 0.25, z, 0, 0, 0);
  f64x4 pc = __builtin_amdgcn_mfma_f64_16x16x4f64(0.25, (double)r16, z, 0, 0, 0);
  int soff0, soff1, soff2, soff3;   // rm*BATCH + cm, packed to 4 regs
  {
    int rm0 = (int)(pr[0] + 0.5), cm0 = (int)(pc[0] + 0.5);
    int rm1 = (int)(pr[1] + 0.5), cm1 = (int)(pc[1] + 0.5);
    int rm2 = (int)(pr[2] + 0.5), cm2 = (int)(pc[2] + 0.5);
    int rm3 = (int)(pr[3] + 0.5), cm3 = (int)(pc[3] + 0.5);
    soff0 = rm0 * BATCH + cm0; soff1 = rm1 * BATCH + cm1;
    soff2 = rm2 * BATCH + cm2; soff3 = rm3 * BATCH + cm3;
  }

  // accumulators: A<nsub><otile>, static names only (rule #20)
  f64x4 A00 = z, A01 = z, A02 = z, A03 = z;
  f64x4 A10 = z, A11 = z, A12 = z, A13 = z;

  // per-wave W base: row q16, col r16 (+64 for wo=1)
  const float* pW0 = W1 + (size_t)q16 * O1 + r16 + (wo ? 64 : 0);

  for (int c = 0; c < NC1; ++c) {
    block_sync_lds();   // previous chunk's compute reads done before rewrite
    // W(c) loads FIRST (oldest-after-ist in vmcnt queue; their latency is
    // covered by ds_write + barrier below)
    float wreg[7][4];
    const float* pWc = pW0 + (size_t)c * (KC1 * O1);
    if (wo == 0) {
#pragma unroll
      for (int q = 0; q < 7; ++q) {
        wreg[q][0] = pWc[q * 400 +  0];
        wreg[q][1] = pWc[q * 400 + 16];
        wreg[q][2] = pWc[q * 400 + 32];
        wreg[q][3] = pWc[q * 400 + 48];
      }
    } else {
#pragma unroll
      for (int q = 0; q < 7; ++q) {
        wreg[q][0] = pWc[q * 400 +  0];
        wreg[q][1] = pWc[q * 400 + 16];
        wreg[q][2] = pWc[q * 400 + 20];
      }
    }
    // ds_write chunk c from regs (waits vmcnt for ist only; W stays in flight)
#pragma unroll
    for (int p = 0; p < 4; ++p)
      if (iact[p]) {
        AI[iq[p] * 2 + 0][irow[p]] = 0.5 * ((double)ist[p].x + (double)ist[p].y);
        AI[iq[p] * 2 + 1][irow[p]] = 0.5 * ((double)ist[p].z + (double)ist[p].w);
      }
    // input prefetch (youngest; survives compute-phase W-wait and barriers)
    if (c + 1 < NC1) {
#pragma unroll
      for (int p = 0; p < 4; ++p)
        if (iact[p]) ist[p] = *reinterpret_cast<const float4*>(ibp[p] + (c + 1) * 56);
    }
    block_sync_lds();   // chunk c visible in LDS
    // compute chunk c: 2 ds_read_b64 + 8(6) MFMA per q-group, W from regs
#define MFMA_(D, A, B) D = __builtin_amdgcn_mfma_f64_16x16x4f64((A), (B), (D), 0, 0, 0)
    if (wo == 0) {
#pragma unroll
      for (int q = 0; q < 7; ++q) {
        const int row = q * 4 + q16;
        const double bv0 = AI[row][wN * 32 + r16];
        const double bv1 = AI[row][wN * 32 + 16 + r16];
        const double w0 = (double)wreg[q][0], w1 = (double)wreg[q][1];
        const double w2 = (double)wreg[q][2], w3 = (double)wreg[q][3];
        MFMA_(A00, w0, bv0); MFMA_(A01, w1, bv0);
        MFMA_(A02, w2, bv0); MFMA_(A03, w3, bv0);
        MFMA_(A10, w0, bv1); MFMA_(A11, w1, bv1);
        MFMA_(A12, w2, bv1); MFMA_(A13, w3, bv1);
      }
    } else {
#pragma unroll
      for (int q = 0; q < 7; ++q) {
        const int row = q * 4 + q16;
        const double bv0 = AI[row][wN * 32 + r16];
        const double bv1 = AI[row][wN * 32 + 16 + r16];
        const double w0 = (double)wreg[q][0], w1 = (double)wreg[q][1];
        const double w2 = (double)wreg[q][2];
        MFMA_(A00, w0, bv0); MFMA_(A01, w1, bv0); MFMA_(A02, w2, bv0);
        MFMA_(A10, w0, bv1); MFMA_(A11, w1, bv1); MFMA_(A12, w2, bv1);
      }
    }
#undef MFMA_
  }

  // epilogue: wave's t-slice = t0 + wN; bv0 accs -> b-offset 0, bv1 -> +16
  double* base = I1T + ((size_t)(t0 + wN) * O1) * BATCH + b0;
#define ST(ACC, O0, BOFF)                                                  \
  {                                                                        \
    base[(size_t)(O0) * BATCH + (BOFF) + soff0] = (ACC)[0];                \
    base[(size_t)(O0) * BATCH + (BOFF) + soff1] = (ACC)[1];                \
    base[(size_t)(O0) * BATCH + (BOFF) + soff2] = (ACC)[2];                \
    base[(size_t)(O0) * BATCH + (BOFF) + soff3] = (ACC)[3];                \
  }
  if (wo == 0) {
    ST(A00, 0, 0);  ST(A01, 16, 0);  ST(A02, 32, 0);  ST(A03, 48, 0);
    ST(A10, 0, 16); ST(A11, 16, 16); ST(A12, 32, 16); ST(A13, 48, 16);
  } else {
    ST(A00, 64, 0);  ST(A01, 80, 0);  ST(A02, 84, 0);
    ST(A10, 64, 16); ST(A11, 80, 16); ST(A12, 84, 16);
  }
#undef ST
}

// ---------------------------------------------------------------------------
// K2: BN stats per (t,o) row: mu, rstd. One wave per row.
// ---------------------------------------------------------------------------
__global__ __launch_bounds__(256) void k2_bnstats(const double* __restrict__ I1T,
                                                  double* __restrict__ mu,
                                                  double* __restrict__ rstd) {
  const int r    = blockIdx.x * 4 + (threadIdx.x >> 6);
  const int lane = threadIdx.x & 63;
  const double2* row2 = reinterpret_cast<const double2*>(I1T + (size_t)r * BATCH) + lane * 4;
  double v[8];
#pragma unroll
  for (int u = 0; u < 4; ++u) {
    double2 p = row2[u];
    v[2 * u] = p.x; v[2 * u + 1] = p.y;
  }
  double s = 0.0;
#pragma unroll
  for (int u = 0; u < 8; ++u) s += v[u];
#pragma unroll
  for (int m = 32; m >= 1; m >>= 1) s += __shfl_xor(s, m, 64);
  const double mean = s / 512.0;
  double q = 0.0;
#pragma unroll
  for (int u = 0; u < 8; ++u) { double d = v[u] - mean; q += d * d; }
#pragma unroll
  for (int m = 32; m >= 1; m >>= 1) q += __shfl_xor(q, m, 64);
  if (lane == 0) {
    mu[r]   = mean;
    rstd[r] = 1.0 / sqrt(q / 512.0 + 1e-5);
  }
}

// ---------------------------------------------------------------------------
// K3: layer-1 LIF scan. Block = o, thread = b.
// ---------------------------------------------------------------------------
__global__ __launch_bounds__(512) void k3_lif1(const double* __restrict__ I1T,
                                               const double* __restrict__ mu,
                                               const double* __restrict__ rstd,
                                               const float* __restrict__ scale,
                                               const float* __restrict__ bias,
                                               float* __restrict__ z1T) {
  const int o = blockIdx.x;
  const int b = threadIdx.x;
  const double sc = (double)scale[o], bs = (double)bias[o];
  double v = 0.0;
  for (int tc = 0; tc < T_STEPS; tc += 10) {
    double x[10], muv[10], rsv[10];
#pragma unroll
    for (int u = 0; u < 10; ++u) {
      const int t = tc + u;
      x[u]   = I1T[((size_t)t * O1 + o) * BATCH + b];
      muv[u] = mu[t * O1 + o];
      rsv[u] = rstd[t * O1 + o];
    }
#pragma unroll
    for (int u = 0; u < 10; ++u) {
      const double i = ((x[u] - muv[u]) * rsv[u]) * sc + bs;
      v = 0.95 * v + i;
      const bool z = (v > 1.0);
      z1T[((size_t)(tc + u) * O1 + o) * BATCH + b] = z ? 1.0f : 0.0f;
      if (z) v = 0.0;
    }
  }
}

// ---------------------------------------------------------------------------
// K4: I2[t][j][b] = sum_o z1T[t][o][b] * W2[o][j].
// ---------------------------------------------------------------------------
__global__ __launch_bounds__(512) void k4_proj2(const float* __restrict__ z1T,
                                                const float* __restrict__ W2,
                                                double* __restrict__ I2) {
  __shared__ double W2_lds[O1 * O2];
  const int t = blockIdx.x;
  const int b = threadIdx.x;
  for (int i = threadIdx.x; i < O1 * O2; i += 512) W2_lds[i] = (double)W2[i];
  __syncthreads();
  double acc[O2];
#pragma unroll
  for (int j = 0; j < O2; ++j) acc[j] = 0.0;
  for (int o = 0; o < O1; ++o) {
    const double z = (double)z1T[((size_t)t * O1 + o) * BATCH + b];
#pragma unroll
    for (int j = 0; j < O2; ++j) acc[j] += z * W2_lds[o * O2 + j];
  }
#pragma unroll
  for (int j = 0; j < O2; ++j)
    I2[((size_t)t * O2 + j) * BATCH + b] = acc[j];
}

// ---------------------------------------------------------------------------
// K5: layer-2 LIF scan + time-mean.
// ---------------------------------------------------------------------------
__global__ __launch_bounds__(512) void k5_lif2(const double* __restrict__ I2,
                                               float* __restrict__ out) {
  const int j = blockIdx.x;
  const int b = threadIdx.x;
  double v = 0.0;
  int cnt = 0;
  for (int tc = 0; tc < T_STEPS; tc += 10) {
    double x[10];
#pragma unroll
    for (int u = 0; u < 10; ++u)
      x[u] = I2[((size_t)(tc + u) * O2 + j) * BATCH + b];
#pragma unroll
    for (int u = 0; u < 10; ++u) {
      v = 0.95 * v + x[u];
      if (v > 1.0) { ++cnt; v = 0.0; }
    }
  }
  out[b * O2 + j] = (float)((double)cnt / 100.0);
}

// ---------------------------------------------------------------------------
extern "C" void kernel_launch(void* const* d_in, const int* in_sizes, int n_in,
                              void* d_out, int out_size, void* d_ws, size_t ws_size,
                              hipStream_t stream) {
  const float* in    = (const float*)d_in[0];
  const float* W1    = (const float*)d_in[2];
  const float* scale = (const float*)d_in[3];
  const float* bias  = (const float*)d_in[4];
  const float* W2    = (const float*)d_in[5];
  float* out = (float*)d_out;

  char* ws = (char*)d_ws;
  size_t off = 0;
  double* I1T  = (double*)(ws + off); off += (size_t)T_STEPS * O1 * BATCH * sizeof(double);
  double* mu   = (double*)(ws + off); off += (size_t)T_STEPS * O1 * sizeof(double);
  double* rstd = (double*)(ws + off); off += (size_t)T_STEPS * O1 * sizeof(double);
  float*  z1T  = (float*)(ws + off);  off += (size_t)T_STEPS * O1 * BATCH * sizeof(float);
  double* I2   = (double*)(ws + off); off += (size_t)T_STEPS * O2 * BATCH * sizeof(double);

  k1_mfma   <<<dim3(BATCH / 32, T_STEPS / 2), 256, 0, stream>>>(in, W1, I1T);
  k2_bnstats<<<dim3(T_STEPS * O1 / 4), 256, 0, stream>>>(I1T, mu, rstd);
  k3_lif1   <<<dim3(O1), 512, 0, stream>>>(I1T, mu, rstd, scale, bias, z1T);
  k4_proj2  <<<dim3(T_STEPS), 512, 0, stream>>>(z1T, W2, I2);
  k5_lif2   <<<dim3(O2), 512, 0, stream>>>(I2, out);
}

// Round 11
// 323.276 us; speedup vs baseline: 2.4655x; 2.4655x over previous
//
#include <hip/hip_runtime.h>

#define T_STEPS 100
#define BATCH   512
#define FIN     784
#define O1      100
#define O2      10
#define KC1     28      // K-chunk (784 = 28 * 28)
#define NC1     (FIN / KC1)

typedef __attribute__((ext_vector_type(4))) double f64x4;

// Raw block barrier draining only LDS (lgkmcnt); global loads stay in flight.
__device__ __forceinline__ void block_sync_lds() {
  __builtin_amdgcn_sched_barrier(0);
  asm volatile("s_waitcnt lgkmcnt(0)" ::: "memory");
  __builtin_amdgcn_s_barrier();
  __builtin_amdgcn_sched_barrier(0);
}

// ---------------------------------------------------------------------------
// K1 v9: fused C-mean + f64 MFMA GEMM, 2-t N-tile. Identical to v8 except
// the launch bound: v8's __launch_bounds__(256,4) forced VGPR<=64 against a
// ~150-reg demand -> accumulators spilled to scratch (WRITE 1.46 GB, FETCH
// 920 MB, 15% MfmaUtil). v9 uses __launch_bounds__(256) only: true
// allocation (~160 VGPR), 2 waves/SIMD, zero spill. Each wave issues 56
// back-to-back MFMAs per chunk; 2 waves/SIMD interleave to feed the pipe.
//   I1T[t][o][b] = sum_f 0.5*(in[b,t,f,0]+in[b,t,f,1]) * W1[f,o]
// Block covers N = (2 t) x (32 b); the SAME W fragment feeds both t-slices:
// 28 W loads + 2 barriers per chunk buy 196 MFMAs (2x rounds 7-9).
// vmcnt queue discipline: ist (prev chunk, oldest) < W(c) < ist(c+1)
// (youngest). ds_write waits only ist; compute waits only W; the input
// prefetch survives both and the lgkm-only barriers.
// ---------------------------------------------------------------------------
__global__ __launch_bounds__(256) void k1_mfma(const float* __restrict__ in,
                                               const float* __restrict__ W1,
                                               double* __restrict__ I1T) {
  __shared__ double AI[KC1][69];    // [f-in-chunk][n], n = tsub*32 + b; pad 69
  const int tid = threadIdx.x;
  const int l   = tid & 63;
  const int w   = tid >> 6;
  const int wN  = w & 1;            // t-slice
  const int wo  = w >> 1;           // o-group
  const int r16 = l & 15;
  const int q16 = l >> 4;
  const int b0  = (int)blockIdx.x * 32;
  const int t0  = (int)blockIdx.y * 2;

  // --- input staging: 64 n-rows x 14 float4 = 896 float4 over 256 threads ---
  bool iact[4]; int irow[4], iq[4]; const float* ibp[4];
#pragma unroll
  for (int p = 0; p < 4; ++p) {
    const int i = p * 256 + tid;
    iact[p] = (i < 896);
    const int nrow = iact[p] ? i / 14 : 0;
    iq[p]   = (iact[p] ? i : 0) - nrow * 14;
    irow[p] = nrow;
    const int tsub = nrow >> 5, brow = nrow & 31;
    ibp[p]  = in + ((size_t)(b0 + brow) * T_STEPS + (t0 + tsub)) * (FIN * 2) + iq[p] * 4;
  }

  // prologue: issue chunk-0 input loads (latency hidden under the probe)
  float4 ist[4];
#pragma unroll
  for (int p = 0; p < 4; ++p) if (iact[p]) ist[p] = *reinterpret_cast<const float4*>(ibp[p]);

  // --- in-kernel D-layout probe (validated rounds 3-10) ---
  const f64x4 z = {0.0, 0.0, 0.0, 0.0};
  f64x4 pr = __builtin_amdgcn_mfma_f64_16x16x4f64((double)r16, 0.25, z, 0, 0, 0);
  f64x4 pc = __builtin_amdgcn_mfma_f64_16x16x4f64(0.25, (double)r16, z, 0, 0, 0);
  int soff0, soff1, soff2, soff3;   // rm*BATCH + cm, packed to 4 regs
  {
    int rm0 = (int)(pr[0] + 0.5), cm0 = (int)(pc[0] + 0.5);
    int rm1 = (int)(pr[1] + 0.5), cm1 = (int)(pc[1] + 0.5);
    int rm2 = (int)(pr[2] + 0.5), cm2 = (int)(pc[2] + 0.5);
    int rm3 = (int)(pr[3] + 0.5), cm3 = (int)(pc[3] + 0.5);
    soff0 = rm0 * BATCH + cm0; soff1 = rm1 * BATCH + cm1;
    soff2 = rm2 * BATCH + cm2; soff3 = rm3 * BATCH + cm3;
  }

  // accumulators: A<nsub><otile>, static names only (rule #20)
  f64x4 A00 = z, A01 = z, A02 = z, A03 = z;
  f64x4 A10 = z, A11 = z, A12 = z, A13 = z;

  // per-wave W base: row q16, col r16 (+64 for wo=1)
  const float* pW0 = W1 + (size_t)q16 * O1 + r16 + (wo ? 64 : 0);

  for (int c = 0; c < NC1; ++c) {
    block_sync_lds();   // previous chunk's compute reads done before rewrite
    // W(c) loads FIRST (older than the c+1 input prefetch; their latency is
    // covered by the ds_write + barrier below)
    float wreg[7][4];
    const float* pWc = pW0 + (size_t)c * (KC1 * O1);
    if (wo == 0) {
#pragma unroll
      for (int q = 0; q < 7; ++q) {
        wreg[q][0] = pWc[q * 400 +  0];
        wreg[q][1] = pWc[q * 400 + 16];
        wreg[q][2] = pWc[q * 400 + 32];
        wreg[q][3] = pWc[q * 400 + 48];
      }
    } else {
#pragma unroll
      for (int q = 0; q < 7; ++q) {
        wreg[q][0] = pWc[q * 400 +  0];
        wreg[q][1] = pWc[q * 400 + 16];
        wreg[q][2] = pWc[q * 400 + 20];
      }
    }
    // ds_write chunk c from regs (waits vmcnt for ist only; W stays in flight)
#pragma unroll
    for (int p = 0; p < 4; ++p)
      if (iact[p]) {
        AI[iq[p] * 2 + 0][irow[p]] = 0.5 * ((double)ist[p].x + (double)ist[p].y);
        AI[iq[p] * 2 + 1][irow[p]] = 0.5 * ((double)ist[p].z + (double)ist[p].w);
      }
    // input prefetch (youngest; survives compute-phase W-wait and barriers)
    if (c + 1 < NC1) {
#pragma unroll
      for (int p = 0; p < 4; ++p)
        if (iact[p]) ist[p] = *reinterpret_cast<const float4*>(ibp[p] + (c + 1) * 56);
    }
    block_sync_lds();   // chunk c visible in LDS
    // compute chunk c: 2 ds_read_b64 + 8(6) MFMA per q-group, W from regs
#define MFMA_(D, A, B) D = __builtin_amdgcn_mfma_f64_16x16x4f64((A), (B), (D), 0, 0, 0)
    if (wo == 0) {
#pragma unroll
      for (int q = 0; q < 7; ++q) {
        const int row = q * 4 + q16;
        const double bv0 = AI[row][wN * 32 + r16];
        const double bv1 = AI[row][wN * 32 + 16 + r16];
        const double w0 = (double)wreg[q][0], w1 = (double)wreg[q][1];
        const double w2 = (double)wreg[q][2], w3 = (double)wreg[q][3];
        MFMA_(A00, w0, bv0); MFMA_(A01, w1, bv0);
        MFMA_(A02, w2, bv0); MFMA_(A03, w3, bv0);
        MFMA_(A10, w0, bv1); MFMA_(A11, w1, bv1);
        MFMA_(A12, w2, bv1); MFMA_(A13, w3, bv1);
      }
    } else {
#pragma unroll
      for (int q = 0; q < 7; ++q) {
        const int row = q * 4 + q16;
        const double bv0 = AI[row][wN * 32 + r16];
        const double bv1 = AI[row][wN * 32 + 16 + r16];
        const double w0 = (double)wreg[q][0], w1 = (double)wreg[q][1];
        const double w2 = (double)wreg[q][2];
        MFMA_(A00, w0, bv0); MFMA_(A01, w1, bv0); MFMA_(A02, w2, bv0);
        MFMA_(A10, w0, bv1); MFMA_(A11, w1, bv1); MFMA_(A12, w2, bv1);
      }
    }
#undef MFMA_
  }

  // epilogue: wave's t-slice = t0 + wN; bv0 accs -> b-offset 0, bv1 -> +16
  double* base = I1T + ((size_t)(t0 + wN) * O1) * BATCH + b0;
#define ST(ACC, O0, BOFF)                                                  \
  {                                                                        \
    base[(size_t)(O0) * BATCH + (BOFF) + soff0] = (ACC)[0];                \
    base[(size_t)(O0) * BATCH + (BOFF) + soff1] = (ACC)[1];                \
    base[(size_t)(O0) * BATCH + (BOFF) + soff2] = (ACC)[2];                \
    base[(size_t)(O0) * BATCH + (BOFF) + soff3] = (ACC)[3];                \
  }
  if (wo == 0) {
    ST(A00, 0, 0);  ST(A01, 16, 0);  ST(A02, 32, 0);  ST(A03, 48, 0);
    ST(A10, 0, 16); ST(A11, 16, 16); ST(A12, 32, 16); ST(A13, 48, 16);
  } else {
    ST(A00, 64, 0);  ST(A01, 80, 0);  ST(A02, 84, 0);
    ST(A10, 64, 16); ST(A11, 80, 16); ST(A12, 84, 16);
  }
#undef ST
}

// ---------------------------------------------------------------------------
// K2: BN stats per (t,o) row: mu, rstd. One wave per row.
// ---------------------------------------------------------------------------
__global__ __launch_bounds__(256) void k2_bnstats(const double* __restrict__ I1T,
                                                  double* __restrict__ mu,
                                                  double* __restrict__ rstd) {
  const int r    = blockIdx.x * 4 + (threadIdx.x >> 6);
  const int lane = threadIdx.x & 63;
  const double2* row2 = reinterpret_cast<const double2*>(I1T + (size_t)r * BATCH) + lane * 4;
  double v[8];
#pragma unroll
  for (int u = 0; u < 4; ++u) {
    double2 p = row2[u];
    v[2 * u] = p.x; v[2 * u + 1] = p.y;
  }
  double s = 0.0;
#pragma unroll
  for (int u = 0; u < 8; ++u) s += v[u];
#pragma unroll
  for (int m = 32; m >= 1; m >>= 1) s += __shfl_xor(s, m, 64);
  const double mean = s / 512.0;
  double q = 0.0;
#pragma unroll
  for (int u = 0; u < 8; ++u) { double d = v[u] - mean; q += d * d; }
#pragma unroll
  for (int m = 32; m >= 1; m >>= 1) q += __shfl_xor(q, m, 64);
  if (lane == 0) {
    mu[r]   = mean;
    rstd[r] = 1.0 / sqrt(q / 512.0 + 1e-5);
  }
}

// ---------------------------------------------------------------------------
// K3: layer-1 LIF scan. Block = o, thread = b.
// ---------------------------------------------------------------------------
__global__ __launch_bounds__(512) void k3_lif1(const double* __restrict__ I1T,
                                               const double* __restrict__ mu,
                                               const double* __restrict__ rstd,
                                               const float* __restrict__ scale,
                                               const float* __restrict__ bias,
                                               float* __restrict__ z1T) {
  const int o = blockIdx.x;
  const int b = threadIdx.x;
  const double sc = (double)scale[o], bs = (double)bias[o];
  double v = 0.0;
  for (int tc = 0; tc < T_STEPS; tc += 10) {
    double x[10], muv[10], rsv[10];
#pragma unroll
    for (int u = 0; u < 10; ++u) {
      const int t = tc + u;
      x[u]   = I1T[((size_t)t * O1 + o) * BATCH + b];
      muv[u] = mu[t * O1 + o];
      rsv[u] = rstd[t * O1 + o];
    }
#pragma unroll
    for (int u = 0; u < 10; ++u) {
      const double i = ((x[u] - muv[u]) * rsv[u]) * sc + bs;
      v = 0.95 * v + i;
      const bool z = (v > 1.0);
      z1T[((size_t)(tc + u) * O1 + o) * BATCH + b] = z ? 1.0f : 0.0f;
      if (z) v = 0.0;
    }
  }
}

// ---------------------------------------------------------------------------
// K4: I2[t][j][b] = sum_o z1T[t][o][b] * W2[o][j].
// ---------------------------------------------------------------------------
__global__ __launch_bounds__(512) void k4_proj2(const float* __restrict__ z1T,
                                                const float* __restrict__ W2,
                                                double* __restrict__ I2) {
  __shared__ double W2_lds[O1 * O2];
  const int t = blockIdx.x;
  const int b = threadIdx.x;
  for (int i = threadIdx.x; i < O1 * O2; i += 512) W2_lds[i] = (double)W2[i];
  __syncthreads();
  double acc[O2];
#pragma unroll
  for (int j = 0; j < O2; ++j) acc[j] = 0.0;
  for (int o = 0; o < O1; ++o) {
    const double z = (double)z1T[((size_t)t * O1 + o) * BATCH + b];
#pragma unroll
    for (int j = 0; j < O2; ++j) acc[j] += z * W2_lds[o * O2 + j];
  }
#pragma unroll
  for (int j = 0; j < O2; ++j)
    I2[((size_t)t * O2 + j) * BATCH + b] = acc[j];
}

// ---------------------------------------------------------------------------
// K5: layer-2 LIF scan + time-mean.
// ---------------------------------------------------------------------------
__global__ __launch_bounds__(512) void k5_lif2(const double* __restrict__ I2,
                                               float* __restrict__ out) {
  const int j = blockIdx.x;
  const int b = threadIdx.x;
  double v = 0.0;
  int cnt = 0;
  for (int tc = 0; tc < T_STEPS; tc += 10) {
    double x[10];
#pragma unroll
    for (int u = 0; u < 10; ++u)
      x[u] = I2[((size_t)(tc + u) * O2 + j) * BATCH + b];
#pragma unroll
    for (int u = 0; u < 10; ++u) {
      v = 0.95 * v + x[u];
      if (v > 1.0) { ++cnt; v = 0.0; }
    }
  }
  out[b * O2 + j] = (float)((double)cnt / 100.0);
}

// ---------------------------------------------------------------------------
extern "C" void kernel_launch(void* const* d_in, const int* in_sizes, int n_in,
                              void* d_out, int out_size, void* d_ws, size_t ws_size,
                              hipStream_t stream) {
  const float* in    = (const float*)d_in[0];
  const float* W1    = (const float*)d_in[2];
  const float* scale = (const float*)d_in[3];
  const float* bias  = (const float*)d_in[4];
  const float* W2    = (const float*)d_in[5];
  float* out = (float*)d_out;

  char* ws = (char*)d_ws;
  size_t off = 0;
  double* I1T  = (double*)(ws + off); off += (size_t)T_STEPS * O1 * BATCH * sizeof(double);
  double* mu   = (double*)(ws + off); off += (size_t)T_STEPS * O1 * sizeof(double);
  double* rstd = (double*)(ws + off); off += (size_t)T_STEPS * O1 * sizeof(double);
  float*  z1T  = (float*)(ws + off);  off += (size_t)T_STEPS * O1 * BATCH * sizeof(float);
  double* I2   = (double*)(ws + off); off += (size_t)T_STEPS * O2 * BATCH * sizeof(double);

  k1_mfma   <<<dim3(BATCH / 32, T_STEPS / 2), 256, 0, stream>>>(in, W1, I1T);
  k2_bnstats<<<dim3(T_STEPS * O1 / 4), 256, 0, stream>>>(I1T, mu, rstd);
  k3_lif1   <<<dim3(O1), 512, 0, stream>>>(I1T, mu, rstd, scale, bias, z1T);
  k4_proj2  <<<dim3(T_STEPS), 512, 0, stream>>>(z1T, W2, I2);
  k5_lif2   <<<dim3(O2), 512, 0, stream>>>(I2, out);
}

// Round 12
// 288.879 us; speedup vs baseline: 2.7590x; 1.1191x over previous
//
#include <hip/hip_runtime.h>

#define T_STEPS 100
#define BATCH   512
#define FIN     784
#define O1      100
#define O2      10
#define KC1     28      // K-chunk (784 = 28 * 28)
#define NC1     (FIN / KC1)

typedef __attribute__((ext_vector_type(4))) double f64x4;

// Raw block barrier draining only LDS (lgkmcnt); global loads stay in flight.
__device__ __forceinline__ void block_sync_lds() {
  __builtin_amdgcn_sched_barrier(0);
  asm volatile("s_waitcnt lgkmcnt(0)" ::: "memory");
  __builtin_amdgcn_s_barrier();
  __builtin_amdgcn_sched_barrier(0);
}

// ---------------------------------------------------------------------------
// K1 v10: fused C-mean + f64 MFMA GEMM.
//   I1T[t][o][b] = sum_f 0.5*(in[b,t,f,0]+in[b,t,f,1]) * W1[f,o]
// Round-11 lesson: 180 regs/wave -> 2 waves/SIMD -> staging overhead exposed
// (MfmaUtil 38%). v10 keeps the MFMA density but rebalances registers and
// SIMDs: block = (64 b x 1 t), 4 waves; EACH wave owns 16 b-rows x ALL 7
// o-tiles -> 49 MFMA/wave-chunk, every SIMD identical. acc = 7 f64x4 (56),
// wreg = 49 f32; total ~150/wave -> 3 waves/SIMD. Per q-group: 1 ds_read_b64
// (bv shared by 7 MFMAs) -> LDS pressure minimal. Grid 8x100 = 800 blocks at
// 3 blocks/CU -> single dispatch round.
// vmcnt discipline: ist(prev, oldest) < W(c) < ist(c+1, youngest); lgkm-only
// barriers keep all of them in flight across sync points.
// o-tiles {0,16,32,48,64,80,84}: tile 84 overlaps 80 -> duplicate stores are
// bitwise identical (same W cols, same MFMA reduction order).
// ---------------------------------------------------------------------------
__global__ __launch_bounds__(256) void k1_mfma(const float* __restrict__ in,
                                               const float* __restrict__ W1,
                                               double* __restrict__ I1T) {
  __shared__ double AI[KC1][69];    // [f-in-chunk][b]; pad 69 spreads banks
  const int tid = threadIdx.x;
  const int l   = tid & 63;
  const int w   = tid >> 6;         // wave id = b-subtile
  const int r16 = l & 15;
  const int q16 = l >> 4;
  const int b0  = (int)blockIdx.x * 64;
  const int t   = (int)blockIdx.y;

  // --- input staging: 64 rows x 14 float4 = 896 float4 over 256 threads ---
  bool iact[4]; int irow[4], iq[4]; const float* ibp[4];
#pragma unroll
  for (int p = 0; p < 4; ++p) {
    const int i = p * 256 + tid;
    iact[p] = (i < 896);
    const int row = iact[p] ? i / 14 : 0;
    iq[p]   = (iact[p] ? i : 0) - row * 14;
    irow[p] = row;
    ibp[p]  = in + ((size_t)(b0 + row) * T_STEPS + t) * (FIN * 2) + iq[p] * 4;
  }

  // prologue: issue chunk-0 input loads (latency hidden under the probe)
  float4 ist[4];
#pragma unroll
  for (int p = 0; p < 4; ++p) if (iact[p]) ist[p] = *reinterpret_cast<const float4*>(ibp[p]);

  // --- in-kernel D-layout probe (validated rounds 3-11) ---
  const f64x4 z = {0.0, 0.0, 0.0, 0.0};
  f64x4 pr = __builtin_amdgcn_mfma_f64_16x16x4f64((double)r16, 0.25, z, 0, 0, 0);
  f64x4 pc = __builtin_amdgcn_mfma_f64_16x16x4f64(0.25, (double)r16, z, 0, 0, 0);
  int soff0, soff1, soff2, soff3;   // rm*BATCH + cm, packed
  {
    int rm0 = (int)(pr[0] + 0.5), cm0 = (int)(pc[0] + 0.5);
    int rm1 = (int)(pr[1] + 0.5), cm1 = (int)(pc[1] + 0.5);
    int rm2 = (int)(pr[2] + 0.5), cm2 = (int)(pc[2] + 0.5);
    int rm3 = (int)(pr[3] + 0.5), cm3 = (int)(pc[3] + 0.5);
    soff0 = rm0 * BATCH + cm0; soff1 = rm1 * BATCH + cm1;
    soff2 = rm2 * BATCH + cm2; soff3 = rm3 * BATCH + cm3;
  }

  // accumulators: one per o-tile, static names only (rule #20)
  f64x4 A0 = z, A1 = z, A2 = z, A3 = z, A4 = z, A5 = z, A6 = z;

  // W base: row q16, col r16; per-tile column offsets are compile-time
  const float* pW0 = W1 + (size_t)q16 * O1 + r16;

  for (int c = 0; c < NC1; ++c) {
    block_sync_lds();   // previous chunk's compute reads done before rewrite
    // W(c) loads FIRST (older than the c+1 prefetch; latency covered by the
    // ds_write + barrier below). 7 q-groups x 7 tiles, all offsets static.
    float wreg[7][7];
    const float* pWc = pW0 + (size_t)c * (KC1 * O1);
#pragma unroll
    for (int q = 0; q < 7; ++q) {
      wreg[q][0] = pWc[q * 400 +  0];
      wreg[q][1] = pWc[q * 400 + 16];
      wreg[q][2] = pWc[q * 400 + 32];
      wreg[q][3] = pWc[q * 400 + 48];
      wreg[q][4] = pWc[q * 400 + 64];
      wreg[q][5] = pWc[q * 400 + 80];
      wreg[q][6] = pWc[q * 400 + 84];
    }
    // ds_write chunk c from regs (waits vmcnt for ist only; W stays in flight)
#pragma unroll
    for (int p = 0; p < 4; ++p)
      if (iact[p]) {
        AI[iq[p] * 2 + 0][irow[p]] = 0.5 * ((double)ist[p].x + (double)ist[p].y);
        AI[iq[p] * 2 + 1][irow[p]] = 0.5 * ((double)ist[p].z + (double)ist[p].w);
      }
    // input prefetch (youngest; survives compute-phase W-wait and barriers)
    if (c + 1 < NC1) {
#pragma unroll
      for (int p = 0; p < 4; ++p)
        if (iact[p]) ist[p] = *reinterpret_cast<const float4*>(ibp[p] + (c + 1) * 56);
    }
    block_sync_lds();   // chunk c visible in LDS
    // compute chunk c: per q-group 1 ds_read_b64 + 7 MFMA (bv shared)
#define MFMA_(D, A, B) D = __builtin_amdgcn_mfma_f64_16x16x4f64((A), (B), (D), 0, 0, 0)
#pragma unroll
    for (int q = 0; q < 7; ++q) {
      const double bv = AI[q * 4 + q16][w * 16 + r16];
      MFMA_(A0, (double)wreg[q][0], bv);
      MFMA_(A1, (double)wreg[q][1], bv);
      MFMA_(A2, (double)wreg[q][2], bv);
      MFMA_(A3, (double)wreg[q][3], bv);
      MFMA_(A4, (double)wreg[q][4], bv);
      MFMA_(A5, (double)wreg[q][5], bv);
      MFMA_(A6, (double)wreg[q][6], bv);
    }
#undef MFMA_
  }

  // epilogue: wave's b-subtile = b0 + 16*w; 7 static tile stores
  double* base = I1T + ((size_t)t * O1) * BATCH + (b0 + w * 16);
#define ST(ACC, O0)                                                        \
  {                                                                        \
    base[(size_t)(O0) * BATCH + soff0] = (ACC)[0];                         \
    base[(size_t)(O0) * BATCH + soff1] = (ACC)[1];                         \
    base[(size_t)(O0) * BATCH + soff2] = (ACC)[2];                         \
    base[(size_t)(O0) * BATCH + soff3] = (ACC)[3];                         \
  }
  ST(A0, 0); ST(A1, 16); ST(A2, 32); ST(A3, 48);
  ST(A4, 64); ST(A5, 80); ST(A6, 84);
#undef ST
}

// ---------------------------------------------------------------------------
// K2: BN stats per (t,o) row: mu, rstd. One wave per row.
// ---------------------------------------------------------------------------
__global__ __launch_bounds__(256) void k2_bnstats(const double* __restrict__ I1T,
                                                  double* __restrict__ mu,
                                                  double* __restrict__ rstd) {
  const int r    = blockIdx.x * 4 + (threadIdx.x >> 6);
  const int lane = threadIdx.x & 63;
  const double2* row2 = reinterpret_cast<const double2*>(I1T + (size_t)r * BATCH) + lane * 4;
  double v[8];
#pragma unroll
  for (int u = 0; u < 4; ++u) {
    double2 p = row2[u];
    v[2 * u] = p.x; v[2 * u + 1] = p.y;
  }
  double s = 0.0;
#pragma unroll
  for (int u = 0; u < 8; ++u) s += v[u];
#pragma unroll
  for (int m = 32; m >= 1; m >>= 1) s += __shfl_xor(s, m, 64);
  const double mean = s / 512.0;
  double q = 0.0;
#pragma unroll
  for (int u = 0; u < 8; ++u) { double d = v[u] - mean; q += d * d; }
#pragma unroll
  for (int m = 32; m >= 1; m >>= 1) q += __shfl_xor(q, m, 64);
  if (lane == 0) {
    mu[r]   = mean;
    rstd[r] = 1.0 / sqrt(q / 512.0 + 1e-5);
  }
}

// ---------------------------------------------------------------------------
// K3: layer-1 LIF scan. Block = o, thread = b.
// ---------------------------------------------------------------------------
__global__ __launch_bounds__(512) void k3_lif1(const double* __restrict__ I1T,
                                               const double* __restrict__ mu,
                                               const double* __restrict__ rstd,
                                               const float* __restrict__ scale,
                                               const float* __restrict__ bias,
                                               float* __restrict__ z1T) {
  const int o = blockIdx.x;
  const int b = threadIdx.x;
  const double sc = (double)scale[o], bs = (double)bias[o];
  double v = 0.0;
  for (int tc = 0; tc < T_STEPS; tc += 10) {
    double x[10], muv[10], rsv[10];
#pragma unroll
    for (int u = 0; u < 10; ++u) {
      const int t = tc + u;
      x[u]   = I1T[((size_t)t * O1 + o) * BATCH + b];
      muv[u] = mu[t * O1 + o];
      rsv[u] = rstd[t * O1 + o];
    }
#pragma unroll
    for (int u = 0; u < 10; ++u) {
      const double i = ((x[u] - muv[u]) * rsv[u]) * sc + bs;
      v = 0.95 * v + i;
      const bool z = (v > 1.0);
      z1T[((size_t)(tc + u) * O1 + o) * BATCH + b] = z ? 1.0f : 0.0f;
      if (z) v = 0.0;
    }
  }
}

// ---------------------------------------------------------------------------
// K4: I2[t][j][b] = sum_o z1T[t][o][b] * W2[o][j].
// ---------------------------------------------------------------------------
__global__ __launch_bounds__(512) void k4_proj2(const float* __restrict__ z1T,
                                                const float* __restrict__ W2,
                                                double* __restrict__ I2) {
  __shared__ double W2_lds[O1 * O2];
  const int t = blockIdx.x;
  const int b = threadIdx.x;
  for (int i = threadIdx.x; i < O1 * O2; i += 512) W2_lds[i] = (double)W2[i];
  __syncthreads();
  double acc[O2];
#pragma unroll
  for (int j = 0; j < O2; ++j) acc[j] = 0.0;
  for (int o = 0; o < O1; ++o) {
    const double z = (double)z1T[((size_t)t * O1 + o) * BATCH + b];
#pragma unroll
    for (int j = 0; j < O2; ++j) acc[j] += z * W2_lds[o * O2 + j];
  }
#pragma unroll
  for (int j = 0; j < O2; ++j)
    I2[((size_t)t * O2 + j) * BATCH + b] = acc[j];
}

// ---------------------------------------------------------------------------
// K5: layer-2 LIF scan + time-mean.
// ---------------------------------------------------------------------------
__global__ __launch_bounds__(512) void k5_lif2(const double* __restrict__ I2,
                                               float* __restrict__ out) {
  const int j = blockIdx.x;
  const int b = threadIdx.x;
  double v = 0.0;
  int cnt = 0;
  for (int tc = 0; tc < T_STEPS; tc += 10) {
    double x[10];
#pragma unroll
    for (int u = 0; u < 10; ++u)
      x[u] = I2[((size_t)(tc + u) * O2 + j) * BATCH + b];
#pragma unroll
    for (int u = 0; u < 10; ++u) {
      v = 0.95 * v + x[u];
      if (v > 1.0) { ++cnt; v = 0.0; }
    }
  }
  out[b * O2 + j] = (float)((double)cnt / 100.0);
}

// ---------------------------------------------------------------------------
extern "C" void kernel_launch(void* const* d_in, const int* in_sizes, int n_in,
                              void* d_out, int out_size, void* d_ws, size_t ws_size,
                              hipStream_t stream) {
  const float* in    = (const float*)d_in[0];
  const float* W1    = (const float*)d_in[2];
  const float* scale = (const float*)d_in[3];
  const float* bias  = (const float*)d_in[4];
  const float* W2    = (const float*)d_in[5];
  float* out = (float*)d_out;

  char* ws = (char*)d_ws;
  size_t off = 0;
  double* I1T  = (double*)(ws + off); off += (size_t)T_STEPS * O1 * BATCH * sizeof(double);
  double* mu   = (double*)(ws + off); off += (size_t)T_STEPS * O1 * sizeof(double);
  double* rstd = (double*)(ws + off); off += (size_t)T_STEPS * O1 * sizeof(double);
  float*  z1T  = (float*)(ws + off);  off += (size_t)T_STEPS * O1 * BATCH * sizeof(float);
  double* I2   = (double*)(ws + off); off += (size_t)T_STEPS * O2 * BATCH * sizeof(double);

  k1_mfma   <<<dim3(BATCH / 64, T_STEPS), 256, 0, stream>>>(in, W1, I1T);
  k2_bnstats<<<dim3(T_STEPS * O1 / 4), 256, 0, stream>>>(I1T, mu, rstd);
  k3_lif1   <<<dim3(O1), 512, 0, stream>>>(I1T, mu, rstd, scale, bias, z1T);
  k4_proj2  <<<dim3(T_STEPS), 512, 0, stream>>>(z1T, W2, I2);
  k5_lif2   <<<dim3(O2), 512, 0, stream>>>(I2, out);
}